// Round 8
// baseline (1179.574 us; speedup 1.0000x reference)
//
#include <hip/hip_runtime.h>
#include <hip/hip_fp16.h>
#include <cstdint>
#include <cstddef>

#define N_NODES_C  100000
#define N_EDGES_C  1600000
#define N_GRAPHS_C 256
#define HID_C      128
// 1/sqrt(1+1e-5)
#define BN_SCALE_C 0.9999950000374997f

#define SCAN_B 1024
#define SCAN_NB ((N_NODES_C + SCAN_B - 1) / SCAN_B)   // 98

typedef _Float16 h8 __attribute__((ext_vector_type(8)));
typedef _Float16 h4 __attribute__((ext_vector_type(4)));
typedef _Float16 hv2 __attribute__((ext_vector_type(2)));
typedef float    f4 __attribute__((ext_vector_type(4)));
typedef float    f2 __attribute__((ext_vector_type(2)));

// ---------------------------------------------------------------------------
// CSR build: histogram of dst, inclusive scan, fused scatter (+f16 ea write).
// ---------------------------------------------------------------------------
__global__ __launch_bounds__(256) void hist_kernel(
    const int* __restrict__ dst, int* __restrict__ counts, int n_edges)
{
    int e = blockIdx.x * 256 + threadIdx.x;
    if (e < n_edges) atomicAdd(&counts[dst[e]], 1);
}

__global__ __launch_bounds__(SCAN_B) void scan1_kernel(
    const int* __restrict__ counts, int* __restrict__ incl,
    int* __restrict__ blocksums, int n)
{
    __shared__ int sdata[SCAN_B];
    const int lid = threadIdx.x;
    const int i = blockIdx.x * SCAN_B + lid;
    sdata[lid] = (i < n) ? counts[i] : 0;
    __syncthreads();
#pragma unroll
    for (int off = 1; off < SCAN_B; off <<= 1) {
        int t = (lid >= off) ? sdata[lid - off] : 0;
        __syncthreads();
        sdata[lid] += t;
        __syncthreads();
    }
    if (i < n) incl[i] = sdata[lid];
    if (lid == SCAN_B - 1) blocksums[blockIdx.x] = sdata[lid];
}

__global__ void scan2_kernel(const int* __restrict__ blocksums,
                             int* __restrict__ blockoffs, int nb)
{
    if (threadIdx.x == 0 && blockIdx.x == 0) {
        int off = 0;
        for (int b = 0; b < nb; ++b) { blockoffs[b] = off; off += blocksums[b]; }
    }
}

__global__ __launch_bounds__(SCAN_B) void scan3_kernel(
    int* __restrict__ incl, const int* __restrict__ blockoffs, int n)
{
    const int i = blockIdx.x * SCAN_B + threadIdx.x;
    if (i < n) incl[i] += blockoffs[blockIdx.x];
}

__global__ __launch_bounds__(256) void initrows_kernel(
    const int* __restrict__ incl, const int* __restrict__ counts,
    int* __restrict__ rowstart, int* __restrict__ cursor, int n)
{
    const int i = blockIdx.x * 256 + threadIdx.x;
    if (i < n) {
        const int rs = incl[i] - counts[i];
        rowstart[i] = rs;
        cursor[i]   = rs;
    }
}

// Fused scatter: place src id AND the f16-converted edge_attr row at the
// CSR slot in one pass (drops perm_eid + the separate permute kernel).
__global__ __launch_bounds__(256) void scatter_fused_kernel(
    const int* __restrict__ src, const int* __restrict__ dst,
    const float* __restrict__ edge_attr,
    int* __restrict__ cursor, int* __restrict__ perm_src,
    _Float16* __restrict__ ea_f16, int n_edges)
{
    const int e = blockIdx.x * 256 + threadIdx.x;
    if (e >= n_edges) return;
    const int pos = atomicAdd(&cursor[dst[e]], 1);
    perm_src[pos] = src[e];
    const float4* p = (const float4*)(edge_attr + (size_t)e * 16);
    const float4 q0 = p[0], q1 = p[1], q2 = p[2], q3 = p[3];
    h8 a, b;
    a[0] = (_Float16)q0.x; a[1] = (_Float16)q0.y;
    a[2] = (_Float16)q0.z; a[3] = (_Float16)q0.w;
    a[4] = (_Float16)q1.x; a[5] = (_Float16)q1.y;
    a[6] = (_Float16)q1.z; a[7] = (_Float16)q1.w;
    b[0] = (_Float16)q2.x; b[1] = (_Float16)q2.y;
    b[2] = (_Float16)q2.z; b[3] = (_Float16)q2.w;
    b[4] = (_Float16)q3.x; b[5] = (_Float16)q3.y;
    b[6] = (_Float16)q3.z; b[7] = (_Float16)q3.w;
    h8* o = (h8*)(ea_f16 + (size_t)pos * 16);
    o[0] = a;
    o[1] = b;
}

// Cast fp32 array -> f16 (vectorized by 4).
__global__ __launch_bounds__(256) void cast_f16_kernel(
    const float* __restrict__ in, _Float16* __restrict__ out, int n4)
{
    const int i = blockIdx.x * 256 + threadIdx.x;
    if (i >= n4) return;
    const float4 v = ((const float4*)in)[i];
    h4 o; o[0] = (_Float16)v.x; o[1] = (_Float16)v.y;
    o[2] = (_Float16)v.z; o[3] = (_Float16)v.w;
    *(h4*)(out + (size_t)i * 4) = o;
}

// Transpose + cast weights: wt[n][k] = (f16) w[k][n].  (tiny, one-time)
__global__ __launch_bounds__(256) void transpose_w_kernel(
    const float* __restrict__ w, _Float16* __restrict__ wt, int K, int N)
{
    const int i = blockIdx.x * 256 + threadIdx.x;
    if (i >= K * N) return;
    const int n = i / K;
    const int k = i - n * K;
    wt[(size_t)n * K + k] = (_Float16)w[(size_t)k * N + n];
}

// ---------------------------------------------------------------------------
// CSR aggregate: quad-per-lane, features-in-lanes packed-f16 MLP.
// Lane owns 4 features as 2 half2 feature-pairs; ea[k] broadcast folds into
// v_pk_fma_f16 op_sel. Per edge: 32 pk_fma + 2 pk_add + 2 pk_max + 4 cvt +
// 4 f32 acc. Unroll x2 keeps 2 gather chains in flight.
// ---------------------------------------------------------------------------
template<int DIN>
__global__ __launch_bounds__(256) void gine_agg_kernel(
    const _Float16* __restrict__ h16, const _Float16* __restrict__ ea_f16,
    const int* __restrict__ perm_src,
    const int* __restrict__ rowstart, const int* __restrict__ rowend,
    const float* __restrict__ ew, const float* __restrict__ eb,
    float* __restrict__ agg, int n_nodes)
{
    constexpr int NQ    = DIN / 4;
    constexpr int SLOTS = 256 / NQ;
    const int fq   = threadIdx.x & (NQ - 1);
    const int slot = threadIdx.x / NQ;
    const int v = blockIdx.x * SLOTS + slot;
    if (v >= n_nodes) return;

    // ew columns for this lane's 2 feature-pairs, f16.
    hv2 ew01[16], ew23[16];
#pragma unroll
    for (int k = 0; k < 16; ++k) {
        const float* wr = ew + (size_t)k * DIN + fq * 4;
        ew01[k][0] = (_Float16)wr[0]; ew01[k][1] = (_Float16)wr[1];
        ew23[k][0] = (_Float16)wr[2]; ew23[k][1] = (_Float16)wr[3];
    }
    hv2 eb01, eb23;
    {
        const float4 ebv = *(const float4*)(eb + fq * 4);
        eb01[0] = (_Float16)ebv.x; eb01[1] = (_Float16)ebv.y;
        eb23[0] = (_Float16)ebv.z; eb23[1] = (_Float16)ebv.w;
    }
    const hv2 zz = {(_Float16)0.f, (_Float16)0.f};

    const int s0 = rowstart[v];
    const int s1 = rowend[v];

    f4 acc = {0.f, 0.f, 0.f, 0.f};
    int j = s0;
    for (; j + 2 <= s1; j += 2) {
        const int sn0 = perm_src[j + 0];
        const int sn1 = perm_src[j + 1];
        const h4 hq0 = *(const h4*)(h16 + (size_t)sn0 * DIN + fq * 4);
        const h4 hq1 = *(const h4*)(h16 + (size_t)sn1 * DIN + fq * 4);
        const h8* p0 = (const h8*)(ea_f16 + (size_t)(j + 0) * 16);
        const h8* p1 = (const h8*)(ea_f16 + (size_t)(j + 1) * 16);
        const h8 a0 = p0[0], a1 = p0[1];
        const h8 b0 = p1[0], b1 = p1[1];

        hv2 c01 = eb01, c23 = eb23;
        hv2 d01 = eb01, d23 = eb23;
#pragma unroll
        for (int k = 0; k < 8; ++k) {
            const hv2 ba = {a0[k], a0[k]};
            const hv2 bb = {b0[k], b0[k]};
            c01 += ba * ew01[k];  c23 += ba * ew23[k];
            d01 += bb * ew01[k];  d23 += bb * ew23[k];
        }
#pragma unroll
        for (int k = 0; k < 8; ++k) {
            const hv2 ba = {a1[k], a1[k]};
            const hv2 bb = {b1[k], b1[k]};
            c01 += ba * ew01[8 + k];  c23 += ba * ew23[8 + k];
            d01 += bb * ew01[8 + k];  d23 += bb * ew23[8 + k];
        }
        const hv2 h001 = {hq0[0], hq0[1]}, h023 = {hq0[2], hq0[3]};
        const hv2 h101 = {hq1[0], hq1[1]}, h123 = {hq1[2], hq1[3]};
        c01 = __builtin_elementwise_max(c01 + h001, zz);
        c23 = __builtin_elementwise_max(c23 + h023, zz);
        d01 = __builtin_elementwise_max(d01 + h101, zz);
        d23 = __builtin_elementwise_max(d23 + h123, zz);
        const f2 r0 = __builtin_convertvector(c01, f2);
        const f2 r1 = __builtin_convertvector(c23, f2);
        const f2 r2 = __builtin_convertvector(d01, f2);
        const f2 r3 = __builtin_convertvector(d23, f2);
        acc[0] += r0[0] + r2[0];
        acc[1] += r0[1] + r2[1];
        acc[2] += r1[0] + r3[0];
        acc[3] += r1[1] + r3[1];
    }
    if (j < s1) {
        const int sn = perm_src[j];
        const h4 hq = *(const h4*)(h16 + (size_t)sn * DIN + fq * 4);
        const h8* p = (const h8*)(ea_f16 + (size_t)j * 16);
        const h8 a0 = p[0], a1 = p[1];
        hv2 c01 = eb01, c23 = eb23;
#pragma unroll
        for (int k = 0; k < 8; ++k) {
            const hv2 ba = {a0[k], a0[k]};
            c01 += ba * ew01[k];  c23 += ba * ew23[k];
        }
#pragma unroll
        for (int k = 0; k < 8; ++k) {
            const hv2 ba = {a1[k], a1[k]};
            c01 += ba * ew01[8 + k];  c23 += ba * ew23[8 + k];
        }
        const hv2 h01 = {hq[0], hq[1]}, h23 = {hq[2], hq[3]};
        c01 = __builtin_elementwise_max(c01 + h01, zz);
        c23 = __builtin_elementwise_max(c23 + h23, zz);
        const f2 r0 = __builtin_convertvector(c01, f2);
        const f2 r1 = __builtin_convertvector(c23, f2);
        acc[0] += r0[0];
        acc[1] += r0[1];
        acc[2] += r1[0];
        acc[3] += r1[1];
    }
    *(f4*)(agg + (size_t)v * DIN + fq * 4) = acc;
}

// ---------------------------------------------------------------------------
// Node kernel (MFMA f16, f16-only node-state I/O): block = 4 waves,
// 16 nodes per wave. A = f16(h16+agg) tile (LDS, +8 pad), B = WT f16
// (global, L2-hot). BN+relu in f32 -> s_t f16 -> mm2 -> relu -> h16 out.
// ---------------------------------------------------------------------------
template<int DIN>
__global__ __launch_bounds__(256) void node_mfma_kernel(
    const _Float16* __restrict__ hin16, const float* __restrict__ agg,
    const _Float16* __restrict__ w1t, const float* __restrict__ b1,
    const float* __restrict__ gm, const float* __restrict__ bt,
    const _Float16* __restrict__ w2t, const float* __restrict__ b2,
    _Float16* __restrict__ h16out, int n_tiles)
{
    constexpr int SXP = DIN + 8;
    constexpr int STP = HID_C + 8;
    __shared__ _Float16 s_x[4][16][SXP];
    __shared__ _Float16 s_t[4][16][STP];

    const int w    = threadIdx.x >> 6;
    const int lane = threadIdx.x & 63;
    int tile = blockIdx.x * 4 + w;
    if (tile >= n_tiles) tile = n_tiles - 1;   // clamp: barriers stay uniform
    const int node0 = tile * 16;

    // ---- stage X = h16 + agg -> f16 LDS tile ----
    constexpr int KQ = DIN / 4;
    for (int it = lane; it < 16 * KQ; it += 64) {
        const int ni = it / KQ;
        const int k4 = (it - ni * KQ) * 4;
        const h4 hv = *(const h4*)(hin16 + (size_t)(node0 + ni) * DIN + k4);
        const float4 av = *(const float4*)(agg + (size_t)(node0 + ni) * DIN + k4);
        h4 o;
        o[0] = (_Float16)((float)hv[0] + av.x);
        o[1] = (_Float16)((float)hv[1] + av.y);
        o[2] = (_Float16)((float)hv[2] + av.z);
        o[3] = (_Float16)((float)hv[3] + av.w);
        *(h4*)&s_x[w][ni][k4] = o;
    }
    __syncthreads();

    const int ln   = lane & 15;
    const int quad = lane >> 4;

    // ---- mm1 + BN + relu -> s_t (f16) ----
#pragma unroll
    for (int nt = 0; nt < 8; ++nt) {
        const int col = nt * 16 + ln;
        const float bv = b1[col];
        f4 acc = {bv, bv, bv, bv};
#pragma unroll
        for (int ks = 0; ks < DIN / 32; ++ks) {
            const h8 af = *(const h8*)&s_x[w][ln][ks * 32 + quad * 8];
            const h8 bf = *(const h8*)(w1t + (size_t)col * DIN + ks * 32 + quad * 8);
            acc = __builtin_amdgcn_mfma_f32_16x16x32_f16(af, bf, acc, 0, 0, 0);
        }
        const float gv = gm[col], btv = bt[col];
#pragma unroll
        for (int r = 0; r < 4; ++r) {
            const float t = fmaxf(fmaf(acc[r] * BN_SCALE_C, gv, btv), 0.f);
            s_t[w][quad * 4 + r][col] = (_Float16)t;
        }
    }
    __syncthreads();

    // ---- mm2 + relu -> h16 out ----
#pragma unroll
    for (int nt = 0; nt < 8; ++nt) {
        const int col = nt * 16 + ln;
        const float bv = b2[col];
        f4 acc = {bv, bv, bv, bv};
#pragma unroll
        for (int ks = 0; ks < HID_C / 32; ++ks) {
            const h8 af = *(const h8*)&s_t[w][ln][ks * 32 + quad * 8];
            const h8 bf = *(const h8*)(w2t + (size_t)col * HID_C + ks * 32 + quad * 8);
            acc = __builtin_amdgcn_mfma_f32_16x16x32_f16(af, bf, acc, 0, 0, 0);
        }
#pragma unroll
        for (int r = 0; r < 4; ++r) {
            const int node = node0 + quad * 4 + r;
            h16out[(size_t)node * HID_C + col] = (_Float16)fmaxf(acc[r], 0.f);
        }
    }
}

// ---------------------------------------------------------------------------
// Pool (reads f16 node state) + output MLP (f32).
// ---------------------------------------------------------------------------
__global__ __launch_bounds__(256) void pool_kernel(
    const _Float16* __restrict__ hfin, const int* __restrict__ batch,
    const float* __restrict__ w1, const float* __restrict__ b1,
    const float* __restrict__ w2, const float* __restrict__ b2,
    float* __restrict__ out, int n_nodes)
{
    const int gid = blockIdx.x;

    int lo = 0, hi = n_nodes;
    while (lo < hi) { int mid = (lo + hi) >> 1; if (batch[mid] < gid) lo = mid + 1; else hi = mid; }
    const int start = lo;
    hi = n_nodes;
    while (lo < hi) { int mid = (lo + hi) >> 1; if (batch[mid] < gid + 1) lo = mid + 1; else hi = mid; }
    const int end = lo;

    const int f = threadIdx.x & (HID_C - 1);
    const int half = threadIdx.x >> 7;

    float sum = 0.f;
    for (int n = start + half; n < end; n += 2)
        sum += (float)hfin[(size_t)n * HID_C + f];

    __shared__ float s_sum[2][HID_C];
    __shared__ float s_p[HID_C];
    __shared__ float s_t[HID_C];
    s_sum[half][f] = sum;
    __syncthreads();

    if (threadIdx.x < HID_C) {
        const float cnt = (float)(end - start);
        s_p[f] = (s_sum[0][f] + s_sum[1][f]) / fmaxf(cnt, 1.f);
    }
    __syncthreads();

    if (threadIdx.x < HID_C) {
        float acc = b1[f];
        for (int k = 0; k < HID_C; ++k) acc = fmaf(s_p[k], w1[k * HID_C + f], acc);
        s_t[f] = fmaxf(acc, 0.f);
    }
    __syncthreads();

    if (threadIdx.x < HID_C) {
        float acc = b2[f];
        for (int k = 0; k < HID_C; ++k) acc = fmaf(s_t[k], w2[k * HID_C + f], acc);
        out[(size_t)gid * HID_C + f] = acc;
    }
}

// ---------------------------------------------------------------------------
extern "C" void kernel_launch(void* const* d_in, const int* in_sizes, int n_in,
                              void* d_out, int out_size, void* d_ws, size_t ws_size,
                              hipStream_t stream)
{
    const float* x         = (const float*)d_in[0];
    const float* edge_attr = (const float*)d_in[1];
    const int*   edge_index= (const int*)  d_in[2];
    const int*   batch     = (const int*)  d_in[3];
    const int*   src = edge_index;
    const int*   dst = edge_index + N_EDGES_C;

    const float* el_w[3] = {(const float*)d_in[4],  (const float*)d_in[12], (const float*)d_in[20]};
    const float* el_b[3] = {(const float*)d_in[5],  (const float*)d_in[13], (const float*)d_in[21]};
    const float* c_w1[3] = {(const float*)d_in[6],  (const float*)d_in[14], (const float*)d_in[22]};
    const float* c_b1[3] = {(const float*)d_in[7],  (const float*)d_in[15], (const float*)d_in[23]};
    const float* c_g [3] = {(const float*)d_in[8],  (const float*)d_in[16], (const float*)d_in[24]};
    const float* c_bt[3] = {(const float*)d_in[9],  (const float*)d_in[17], (const float*)d_in[25]};
    const float* c_w2[3] = {(const float*)d_in[10], (const float*)d_in[18], (const float*)d_in[26]};
    const float* c_b2[3] = {(const float*)d_in[11], (const float*)d_in[19], (const float*)d_in[27]};
    const float* o_w1 = (const float*)d_in[28];
    const float* o_b1 = (const float*)d_in[29];
    const float* o_w2 = (const float*)d_in[30];
    const float* o_b2 = (const float*)d_in[31];

    // ---- workspace layout (~155 MB) ----
    char* wsp = (char*)d_ws;
    size_t used = 0;
    auto alloc = [&](size_t bytes) { char* p = wsp + used; used += (bytes + 255) & ~(size_t)255; return p; };
    float* agg      = (float*)alloc((size_t)N_NODES_C * HID_C * 4);
    int*   counts   = (int*)alloc((size_t)N_NODES_C * 4);
    int*   incl     = (int*)alloc((size_t)N_NODES_C * 4);
    int*   rowstart = (int*)alloc((size_t)N_NODES_C * 4);
    int*   cursor   = (int*)alloc((size_t)N_NODES_C * 4);
    int*   blocksums= (int*)alloc(128 * 4);
    int*   blockoffs= (int*)alloc(128 * 4);
    int*   perm_src = (int*)alloc((size_t)N_EDGES_C * 4);
    _Float16* ea_f16 = (_Float16*)alloc((size_t)N_EDGES_C * 16 * 2);
    _Float16* h_f16  = (_Float16*)alloc((size_t)N_NODES_C * HID_C * 2);
    _Float16* x_f16  = (_Float16*)alloc((size_t)N_NODES_C * 64 * 2);
    _Float16* w1t[3], *w2t[3];
    for (int l = 0; l < 3; ++l) {
        w1t[l] = (_Float16*)alloc((size_t)HID_C * HID_C * 2);
        w2t[l] = (_Float16*)alloc((size_t)HID_C * HID_C * 2);
    }
    (void)ws_size;

    // ---- CSR build (once; reused by all 3 layers) ----
    hipMemsetAsync(counts, 0, (size_t)N_NODES_C * 4, stream);
    hist_kernel<<<(N_EDGES_C + 255) / 256, 256, 0, stream>>>(dst, counts, N_EDGES_C);
    scan1_kernel<<<SCAN_NB, SCAN_B, 0, stream>>>(counts, incl, blocksums, N_NODES_C);
    scan2_kernel<<<1, 64, 0, stream>>>(blocksums, blockoffs, SCAN_NB);
    scan3_kernel<<<SCAN_NB, SCAN_B, 0, stream>>>(incl, blockoffs, N_NODES_C);
    initrows_kernel<<<(N_NODES_C + 255) / 256, 256, 0, stream>>>(incl, counts, rowstart,
                                                                 cursor, N_NODES_C);
    scatter_fused_kernel<<<(N_EDGES_C + 255) / 256, 256, 0, stream>>>(
        src, dst, edge_attr, cursor, perm_src, ea_f16, N_EDGES_C);
    cast_f16_kernel<<<(N_NODES_C * 64 / 4 + 255) / 256, 256, 0, stream>>>(
        x, x_f16, N_NODES_C * 64 / 4);
    for (int l = 0; l < 3; ++l) {
        const int K1 = (l == 0) ? 64 : HID_C;
        transpose_w_kernel<<<(K1 * HID_C + 255) / 256, 256, 0, stream>>>(
            c_w1[l], w1t[l], K1, HID_C);
        transpose_w_kernel<<<(HID_C * HID_C + 255) / 256, 256, 0, stream>>>(
            c_w2[l], w2t[l], HID_C, HID_C);
    }

    const int n_tiles = N_NODES_C / 16;            // 6250
    const int nb_node = (n_tiles + 3) / 4;         // 1563

    // ---- 3 GINE layers ----
    for (int l = 0; l < 3; ++l) {
        if (l == 0) {
            gine_agg_kernel<64><<<(N_NODES_C + 15) / 16, 256, 0, stream>>>(
                x_f16, ea_f16, perm_src, rowstart, incl,
                el_w[0], el_b[0], agg, N_NODES_C);
            node_mfma_kernel<64><<<nb_node, 256, 0, stream>>>(
                x_f16, agg, w1t[0], c_b1[0], c_g[0], c_bt[0], w2t[0], c_b2[0],
                h_f16, n_tiles);
        } else {
            gine_agg_kernel<128><<<(N_NODES_C + 7) / 8, 256, 0, stream>>>(
                h_f16, ea_f16, perm_src, rowstart, incl,
                el_w[l], el_b[l], agg, N_NODES_C);
            node_mfma_kernel<128><<<nb_node, 256, 0, stream>>>(
                h_f16, agg, w1t[l], c_b1[l], c_g[l], c_bt[l], w2t[l], c_b2[l],
                h_f16, n_tiles);
        }
    }

    // ---- pool + output MLP ----
    pool_kernel<<<N_GRAPHS_C, 256, 0, stream>>>(h_f16, batch, o_w1, o_b1, o_w2, o_b2,
                                                (float*)d_out, N_NODES_C);
}